// Round 16
// baseline (907.402 us; speedup 1.0000x reference)
//
#include <hip/hip_runtime.h>
#include <hip/hip_bf16.h>

typedef unsigned short u16;
typedef __bf16 bf16x8 __attribute__((ext_vector_type(8)));
typedef float f32x4 __attribute__((ext_vector_type(4)));

#define DEVINL __device__ __forceinline__

DEVINL u16 f2b(float f){
  unsigned u = __float_as_uint(f);
  u += 0x7FFFu + ((u >> 16) & 1u);   // RNE
  return (u16)(u >> 16);
}
DEVINL float b2f(u16 b){ return __uint_as_float(((unsigned)b) << 16); }

DEVINL void gload16(const void* g, void* l){
  __builtin_amdgcn_global_load_lds(
      (const __attribute__((address_space(1))) unsigned*)g,
      (__attribute__((address_space(3))) unsigned*)l, 16, 0, 0);
}

// raw barrier: does NOT drain vmcnt (unlike __syncthreads) — counted prefetch survives.
DEVINL void rawbar(){
  __builtin_amdgcn_sched_barrier(0);
  __builtin_amdgcn_s_barrier();
  __builtin_amdgcn_sched_barrier(0);
}

// ---------------- embeddings ----------------
__global__ __launch_bounds__(256) void k_embed(const int* __restrict__ idx,
    const float* __restrict__ tok, const float* __restrict__ pos, float* __restrict__ h){
  int r = blockIdx.x, t = threadIdx.x;
  int token = idx[r];
  const float* tr = tok + (long)token * 768;
  const float* pr = pos + (long)(r & 1023) * 768;
  float* hr = h + (long)r * 768;
  hr[t]       = tr[t]       + pr[t];
  hr[t + 256] = tr[t + 256] + pr[t + 256];
  hr[t + 512] = tr[t + 512] + pr[t + 512];
}

// ---------------- layernorm fp32 -> bf16 ----------------
__global__ __launch_bounds__(256) void k_ln(const float* __restrict__ X,
    const float* __restrict__ s, const float* __restrict__ b, u16* __restrict__ Y){
  int r = blockIdx.x, t = threadIdx.x;
  const float* x = X + (long)r * 768;
  float v0 = x[t], v1 = x[t + 256], v2 = x[t + 512];
  float sum = v0 + v1 + v2;
  __shared__ float tmp[4];
  #pragma unroll
  for (int o = 32; o; o >>= 1) sum += __shfl_xor(sum, o);
  int wave = t >> 6;
  if ((t & 63) == 0) tmp[wave] = sum;
  __syncthreads();
  sum = tmp[0] + tmp[1] + tmp[2] + tmp[3];
  float m = sum * (1.f / 768.f);
  float d0 = v0 - m, d1 = v1 - m, d2 = v2 - m;
  float sq = d0 * d0 + d1 * d1 + d2 * d2;
  #pragma unroll
  for (int o = 32; o; o >>= 1) sq += __shfl_xor(sq, o);
  __syncthreads();
  if ((t & 63) == 0) tmp[wave] = sq;
  __syncthreads();
  sq = tmp[0] + tmp[1] + tmp[2] + tmp[3];
  float rs = rsqrtf(sq * (1.f / 768.f) + 1e-5f);
  u16* y = Y + (long)r * 768;
  y[t]       = f2b(d0 * rs * s[t]       + b[t]);
  y[t + 256] = f2b(d1 * rs * s[t + 256] + b[t + 256]);
  y[t + 512] = f2b(d2 * rs * s[t + 512] + b[t + 512]);
}

// ---------------- weight transpose + fp32->bf16 ----------------
__global__ __launch_bounds__(256) void k_wt(const float* __restrict__ W, u16* __restrict__ Wt,
                                            int K, int N){
  __shared__ float tile[32][33];
  int kb = blockIdx.x * 32, nb = blockIdx.y * 32;
  int tx = threadIdx.x & 31, ty = threadIdx.x >> 5;
  #pragma unroll
  for (int i = 0; i < 32; i += 8) tile[ty + i][tx] = W[(long)(kb + ty + i) * N + nb + tx];
  __syncthreads();
  #pragma unroll
  for (int i = 0; i < 32; i += 8) Wt[(long)(nb + ty + i) * K + kb + tx] = f2b(tile[tx][ty + i]);
}

// ---------------- fp32 -> bf16 convert ----------------
__global__ __launch_bounds__(256) void k_conv(const float* __restrict__ W, u16* __restrict__ O, long n4){
  long i = (long)blockIdx.x * 256 + threadIdx.x;
  if (i >= n4) return;
  float4 v = ((const float4*)W)[i];
  unsigned lo = (unsigned)f2b(v.x) | ((unsigned)f2b(v.y) << 16);
  unsigned hi = (unsigned)f2b(v.z) | ((unsigned)f2b(v.w) << 16);
  ((uint2*)O)[i] = make_uint2(lo, hi);
}

// ---------------- router GEMM1 (fp32) ----------------
__global__ __launch_bounds__(256) void k_r1(const float* __restrict__ A, const float* __restrict__ B,
    const float* __restrict__ bias, float* __restrict__ C){
  __shared__ float As[64][17];
  __shared__ float Bs[16][65];
  int r0 = blockIdx.x * 64, c0 = blockIdx.y * 64;
  int t = threadIdx.x;
  int tx = t & 15, ty = t >> 4;
  float acc[4][4] = {};
  for (int k0 = 0; k0 < 768; k0 += 16){
    #pragma unroll
    for (int i = 0; i < 4; i++){ int e = i * 256 + t; As[e >> 4][e & 15] = A[(long)(r0 + (e >> 4)) * 768 + k0 + (e & 15)]; }
    #pragma unroll
    for (int i = 0; i < 4; i++){ int e = i * 256 + t; Bs[e >> 6][e & 63] = B[(long)(k0 + (e >> 6)) * 384 + c0 + (e & 63)]; }
    __syncthreads();
    #pragma unroll
    for (int kk = 0; kk < 16; kk++){
      float a[4], bb[4];
      #pragma unroll
      for (int i = 0; i < 4; i++) a[i] = As[ty * 4 + i][kk];
      #pragma unroll
      for (int j = 0; j < 4; j++) bb[j] = Bs[kk][tx * 4 + j];
      #pragma unroll
      for (int i = 0; i < 4; i++)
        #pragma unroll
        for (int j = 0; j < 4; j++) acc[i][j] += a[i] * bb[j];
    }
    __syncthreads();
  }
  #pragma unroll
  for (int i = 0; i < 4; i++)
    #pragma unroll
    for (int j = 0; j < 4; j++){
      int rr = r0 + ty * 4 + i, cc = c0 + tx * 4 + j;
      float v = acc[i][j] + bias[cc];
      C[(long)rr * 384 + cc] = v > 0.f ? v : 0.f;
    }
}

// ---------------- router GEMM2 + argmax (fp32) ----------------
__global__ __launch_bounds__(64) void k_r2(const float* __restrict__ rh, const float* __restrict__ w2,
    const float* __restrict__ b2, int* __restrict__ sel){
  int tkn = blockIdx.x, l = threadIdx.x;
  float s0 = 0, s1 = 0, s2 = 0, s3 = 0;
  const float* r = rh + (long)tkn * 384;
  for (int k = l; k < 384; k += 64){
    float rv = r[k];
    float4 w = ((const float4*)w2)[k];
    s0 += rv * w.x; s1 += rv * w.y; s2 += rv * w.z; s3 += rv * w.w;
  }
  #pragma unroll
  for (int o = 32; o; o >>= 1){
    s0 += __shfl_xor(s0, o); s1 += __shfl_xor(s1, o);
    s2 += __shfl_xor(s2, o); s3 += __shfl_xor(s3, o);
  }
  if (l == 0){
    float v[4] = { s0 + b2[0], s1 + b2[1], s2 + b2[2], s3 + b2[3] };
    int am = 0; float bv = v[0];
    #pragma unroll
    for (int j = 1; j < 4; j++) if (v[j] > bv){ bv = v[j]; am = j; }
    sel[tkn] = am;
  }
}

// ---------------- fused causal flash attention ----------------
__global__ __launch_bounds__(256) void k_attn(
    const u16* __restrict__ qkv, const u16* __restrict__ Vt, u16* __restrict__ o){
  __shared__ __align__(16) u16 Klds[64][64];
  __shared__ __align__(16) u16 Vlds[64][64];
  __shared__ __align__(16) u16 Plds[4][16][72];
  int qt = (gridDim.x - 1) - blockIdx.x;   // long blocks (large qt) launch first
  int bh = blockIdx.y;
  int b = bh / 12, hh = bh % 12;
  int t = threadIdx.x, w = t >> 6, lane = t & 63;
  int lr = lane & 15, koct = lane >> 4;
  int q0 = qt * 64 + w * 16;
  const u16* Qrow = qkv + ((long)(b * 1024 + q0 + lr)) * 2304 + hh * 64;
  bf16x8 qf[2];
  qf[0] = __builtin_bit_cast(bf16x8, *(const uint4*)&Qrow[koct * 8]);
  qf[1] = __builtin_bit_cast(bf16x8, *(const uint4*)&Qrow[32 + koct * 8]);
  f32x4 oacc[4] = {};
  float m_run[4], l_run[4];
  #pragma unroll
  for (int r = 0; r < 4; r++){ m_run[r] = -1e30f; l_run[r] = 0.f; }
  int srow8 = lane >> 3, scolb = (lane & 7) * 16;
  const char* Kbase = (const char*)(qkv + (long)b * 1024 * 2304 + 768 + hh * 64);
  const char* Vbase = (const char*)(Vt + (long)bh * 64 * 1024);
  for (int kvt = 0; kvt <= qt; ++kvt){
    #pragma unroll
    for (int i = 0; i < 2; i++){
      int row = w * 16 + i * 8 + srow8;
      int sb = scolb ^ ((row & 7) << 4);
      gload16(Kbase + (long)(kvt * 64 + row) * 4608 + sb, &Klds[w * 16 + i * 8][0]);
    }
    #pragma unroll
    for (int i = 0; i < 2; i++){
      int row = w * 16 + i * 8 + srow8;
      int sb = scolb ^ ((row & 7) << 4);
      gload16(Vbase + (long)row * 2048 + kvt * 128 + sb, &Vlds[w * 16 + i * 8][0]);
    }
    __syncthreads();
    f32x4 sacc[4] = {};
    #pragma unroll
    for (int j = 0; j < 4; j++){
      #pragma unroll
      for (int f = 0; f < 2; f++){
        int row = 16 * j + lr;
        bf16x8 kf = __builtin_bit_cast(bf16x8, *(const uint4*)(
            (const char*)&Klds[0][0] + row * 128 + ((64 * f + koct * 16) ^ ((row & 7) << 4))));
        sacc[j] = __builtin_amdgcn_mfma_f32_16x16x32_bf16(qf[f], kf, sacc[j], 0, 0, 0);
      }
    }
    bool diag = (kvt == qt);
    float p[4][4];
    #pragma unroll
    for (int r = 0; r < 4; r++){
      int qg = q0 + 4 * koct + r;
      float vj[4];
      #pragma unroll
      for (int j = 0; j < 4; j++){
        int kvg = kvt * 64 + 16 * j + lr;
        float v = sacc[j][r] * 0.125f;
        vj[j] = (!diag || kvg <= qg) ? v : -1e30f;
      }
      float mx = fmaxf(fmaxf(vj[0], vj[1]), fmaxf(vj[2], vj[3]));
      #pragma unroll
      for (int s = 1; s < 16; s <<= 1) mx = fmaxf(mx, __shfl_xor(mx, s));
      float mn = fmaxf(m_run[r], mx);
      float sc = __expf(m_run[r] - mn);
      float rs = 0.f;
      #pragma unroll
      for (int j = 0; j < 4; j++){ p[j][r] = __expf(vj[j] - mn); rs += p[j][r]; }
      #pragma unroll
      for (int s = 1; s < 16; s <<= 1) rs += __shfl_xor(rs, s);
      l_run[r] = l_run[r] * sc + rs;
      m_run[r] = mn;
      #pragma unroll
      for (int j = 0; j < 4; j++) oacc[j][r] *= sc;
    }
    #pragma unroll
    for (int r = 0; r < 4; r++)
      #pragma unroll
      for (int j = 0; j < 4; j++)
        Plds[w][4 * koct + r][16 * j + lr] = f2b(p[j][r]);
    bf16x8 pf[2];
    pf[0] = __builtin_bit_cast(bf16x8, *(const uint4*)&Plds[w][lr][koct * 8]);
    pf[1] = __builtin_bit_cast(bf16x8, *(const uint4*)&Plds[w][lr][32 + koct * 8]);
    #pragma unroll
    for (int j = 0; j < 4; j++){
      #pragma unroll
      for (int f = 0; f < 2; f++){
        int row = 16 * j + lr;
        bf16x8 vf = __builtin_bit_cast(bf16x8, *(const uint4*)(
            (const char*)&Vlds[0][0] + row * 128 + ((64 * f + koct * 16) ^ ((row & 7) << 4))));
        oacc[j] = __builtin_amdgcn_mfma_f32_16x16x32_bf16(pf[f], vf, oacc[j], 0, 0, 0);
      }
    }
    __syncthreads();
  }
  float inv[4];
  #pragma unroll
  for (int r = 0; r < 4; r++) inv[r] = 1.f / l_run[r];
  #pragma unroll
  for (int j = 0; j < 4; j++){
    #pragma unroll
    for (int r = 0; r < 4; r++){
      int tq = b * 1024 + q0 + 4 * koct + r;
      o[(long)tq * 768 + hh * 64 + 16 * j + lr] = f2b(oacc[j][r] * inv[r]);
    }
  }
}

// ---------------- split-K reduce (bf16 partials) + bias + resid -> h; fused LN -> y; depth-select ----------------
__global__ __launch_bounds__(256) void k_redln(const u16* __restrict__ P, int nparts,
    const float* __restrict__ bias, const float* __restrict__ resid, float* __restrict__ outh,
    const float* __restrict__ ls, const float* __restrict__ lb, u16* __restrict__ Y,
    const int* __restrict__ sel, float* __restrict__ outb, int d){
  int r = blockIdx.x, t = threadIdx.x;
  float v0, v1, v2;
  {
    float a0 = bias[t]       + resid[(long)r * 768 + t];
    float a1 = bias[t + 256] + resid[(long)r * 768 + t + 256];
    float a2 = bias[t + 512] + resid[(long)r * 768 + t + 512];
    for (int p = 0; p < nparts; p++){
      const u16* pr = P + ((long)p * 2048 + r) * 768;
      a0 += b2f(pr[t]); a1 += b2f(pr[t + 256]); a2 += b2f(pr[t + 512]);
    }
    v0 = a0; v1 = a1; v2 = a2;
  }
  float* hr = outh + (long)r * 768;
  hr[t] = v0; hr[t + 256] = v1; hr[t + 512] = v2;
  if (sel && sel[r] == d){
    float* orow = outb + (long)r * 768;
    orow[t] = v0; orow[t + 256] = v1; orow[t + 512] = v2;
  }
  float sum = v0 + v1 + v2;
  __shared__ float tmp[4];
  #pragma unroll
  for (int o = 32; o; o >>= 1) sum += __shfl_xor(sum, o);
  int wave = t >> 6;
  if ((t & 63) == 0) tmp[wave] = sum;
  __syncthreads();
  sum = tmp[0] + tmp[1] + tmp[2] + tmp[3];
  float m = sum * (1.f / 768.f);
  float d0 = v0 - m, d1 = v1 - m, d2 = v2 - m;
  float sq = d0 * d0 + d1 * d1 + d2 * d2;
  #pragma unroll
  for (int o = 32; o; o >>= 1) sq += __shfl_xor(sq, o);
  __syncthreads();
  if ((t & 63) == 0) tmp[wave] = sq;
  __syncthreads();
  sq = tmp[0] + tmp[1] + tmp[2] + tmp[3];
  float rs = rsqrtf(sq * (1.f / 768.f) + 1e-5f);
  u16* y = Y + (long)r * 768;
  y[t]       = f2b(d0 * rs * ls[t]       + lb[t]);
  y[t + 256] = f2b(d1 * rs * ls[t + 256] + lb[t + 256]);
  y[t + 512] = f2b(d2 * rs * ls[t + 512] + lb[t + 512]);
}

// ---------------- f1 reduce: ffh = gelu(bias + P0 + P1); P0 aliases ffh (per-element read-then-write) ----------------
__global__ __launch_bounds__(256) void k_redg2(const u16* __restrict__ P1,
    const float* __restrict__ bias, u16* __restrict__ P0_out){
  int r = blockIdx.x, t = threadIdx.x;
  #pragma unroll
  for (int k = 0; k < 12; k++){
    int c = t + k * 256;
    long idx = (long)r * 3072 + c;
    float a = bias[c] + b2f(P0_out[idx]) + b2f(P1[idx]);
    a = 0.5f * a * (1.f + erff(a * 0.70710678118654752f));
    P0_out[idx] = f2b(a);
  }
}

// ---------------- 1-wave 64x64 bf16 MFMA GEMM, dbuf + counted vmcnt, slot-XOR swizzled LDS ----------------
__global__ __launch_bounds__(64) void k_gemm1(
    const u16* __restrict__ A, int lda, long s1A, long s2A,
    const u16* __restrict__ B, int ldb, long s1B, long s2B,
    void* Cv, int ldc, long s1C, long s2C,
    const float* __restrict__ bias,
    const float* __restrict__ resid, int ldr,
    int K, int zdiv, int ksegK, int flags, u16* __restrict__ vtbuf){
  __shared__ __align__(16) u16 As[2][64][32];
  __shared__ __align__(16) u16 Bs[2][64][32];
  int lane = threadIdx.x;
  int bx = blockIdx.x, by = blockIdx.y, bz = blockIdx.z;
  if (flags & 16){
    int nx = gridDim.x, nwg = nx * gridDim.y;
    int lin = by * nx + bx;
    int q = nwg >> 3;                       // requires nwg % 8 == 0
    int nl = (lin & 7) * q + (lin >> 3);
    bx = nl % nx; by = nl / nx;
  }
  int row0 = bx * 64, col0 = by * 64;
  int zq = bz / zdiv, zr = bz % zdiv;
  A += zq * s2A + (long)zr * s1A;
  B += zq * s2B + (long)zr * s1B;
  long coff = zq * s2C + (long)zr * s1C;
  int kstart = 0, Klim = K;
  if (ksegK > 0){ kstart = bz * ksegK; Klim = kstart + ksegK; }
  f32x4 acc[4][4] = {};
  int lr = lane & 15;
  int lkb = (lane >> 4) * 16;                       // 16B slot (bytes) within 64B row
  int srow = lane >> 2, scol = (lane & 3) * 16;
  int sg = ((srow >> 1) & 3) << 4;                  // source inverse-swizzle for this lane's row
  int rg = ((lr >> 1) & 3) << 4;                    // read swizzle for this lane's fragment row
  int nt = (Klim - kstart) >> 5;
  auto STAGE = [&](int buf, int k0){
    #pragma unroll
    for (int i = 0; i < 4; i++)
      gload16((const char*)&A[(long)(row0 + i * 16 + srow) * lda + k0] + (scol ^ sg), &As[buf][i * 16][0]);
    #pragma unroll
    for (int i = 0; i < 4; i++)
      gload16((const char*)&B[(long)(col0 + i * 16 + srow) * ldb + k0] + (scol ^ sg), &Bs[buf][i * 16][0]);
  };
  STAGE(0, kstart);
  int cur = 0;
  for (int t = 0; t < nt; t++){
    if (t + 1 < nt){
      STAGE(cur ^ 1, kstart + ((t + 1) << 5));
      asm volatile("s_waitcnt vmcnt(8)" ::: "memory");
    } else {
      asm volatile("s_waitcnt vmcnt(0)" ::: "memory");
    }
    __builtin_amdgcn_sched_barrier(0);
    bf16x8 af[4], bb[4];
    #pragma unroll
    for (int i = 0; i < 4; i++)
      af[i] = __builtin_bit_cast(bf16x8, *(const uint4*)(
          (const char*)&As[cur][i * 16 + lr][0] + (lkb ^ rg)));
    #pragma unroll
    for (int j = 0; j < 4; j++)
      bb[j] = __builtin_bit_cast(bf16x8, *(const uint4*)(
          (const char*)&Bs[cur][j * 16 + lr][0] + (lkb ^ rg)));
    #pragma unroll
    for (int i = 0; i < 4; i++)
      #pragma unroll
      for (int j = 0; j < 4; j++)
        acc[i][j] = __builtin_amdgcn_mfma_f32_16x16x32_bf16(af[i], bb[j], acc[i][j], 0, 0, 0);
    __builtin_amdgcn_sched_barrier(0);
    cur ^= 1;
  }
  bool vmode = (vtbuf != nullptr) && (col0 >= 1536);
  if (vmode){
    #pragma unroll
    for (int i = 0; i < 4; i++){
      int rbase = row0 + i * 16 + ((lane >> 4) << 2);
      int b = rbase >> 10, tt = rbase & 1023;
      #pragma unroll
      for (int j = 0; j < 4; j++){
        int cc = col0 + j * 16 + lr;
        int hh = (cc - 1536) >> 6, dd = (cc - 1536) & 63;
        unsigned lo = (unsigned)f2b(acc[i][j][0]) | ((unsigned)f2b(acc[i][j][1]) << 16);
        unsigned hi = (unsigned)f2b(acc[i][j][2]) | ((unsigned)f2b(acc[i][j][3]) << 16);
        *(uint2*)&vtbuf[((long)(b * 12 + hh) * 64 + dd) * 1024 + tt] = make_uint2(lo, hi);
      }
    }
    return;
  }
  #pragma unroll
  for (int i = 0; i < 4; i++){
    int rbase = row0 + i * 16 + ((lane >> 4) << 2);
    #pragma unroll
    for (int j = 0; j < 4; j++){
      int cc = col0 + j * 16 + lr;
      #pragma unroll
      for (int q = 0; q < 4; q++){
        int rr = rbase + q;
        float v = acc[i][j][q];
        if (bias) v += bias[cc];
        if (flags & 2) v = 0.5f * v * (1.f + erff(v * 0.70710678118654752f));
        if (resid) v += resid[(long)rr * ldr + cc];
        if (flags & 1) ((u16*)Cv)[coff + (long)rr * ldc + cc] = f2b(v);
        else           ((float*)Cv)[coff + (long)rr * ldc + cc] = v;
      }
    }
  }
}

// ---------------- head GEMM: 256x256, 8 waves, BK=32, 64KB LDS (2 blocks/CU), counted vmcnt + RAW barriers ----------------
// C[2048,32000] fp32 = A[2048,768]bf16 @ B[32000,768]bf16^T
__global__ __launch_bounds__(512, 2) void k_head(
    const u16* __restrict__ A, const u16* __restrict__ B, float* __restrict__ C){
  __shared__ __align__(16) u16 As[2][256][32];   // 16 KB per buf
  __shared__ __align__(16) u16 Bs[2][256][32];   // total 64 KB -> 2 blocks/CU
  const int lda = 768, ldb = 768, ldc = 32000;
  int t = threadIdx.x, w = t >> 6, lane = t & 63;
  int wm = w >> 2, wn = w & 3;                   // 2 x 4 wave grid
  int bx = blockIdx.x, by = blockIdx.y;
  {
    int nx = gridDim.x, nwg = nx * gridDim.y;    // 8*125 = 1000, %8 == 0
    int lin = by * nx + bx;
    int q = nwg >> 3;
    int nl = (lin & 7) * q + (lin >> 3);
    bx = nl % nx; by = nl / nx;
  }
  long row0 = (long)bx * 256, col0 = (long)by * 256;
  int srow = lane >> 2, sslot = (lane & 3) * 16;
  int lr = lane & 15, koct = lane >> 4;
  f32x4 acc[8][4] = {};
  const int nt = 24;                             // K = 768 = 24 * 32
  auto STAGE_A = [&](int buf, int k0){
    #pragma unroll
    for (int g = 0; g < 2; g++){
      int row = g * 128 + w * 16 + srow;
      gload16((const char*)&A[(row0 + row) * lda + k0] + (sslot ^ (((row >> 1) & 3) << 4)),
              &As[buf][g * 128 + w * 16][0]);
    }
  };
  auto STAGE_B = [&](int buf, int k0){
    #pragma unroll
    for (int g = 0; g < 2; g++){
      int row = g * 128 + w * 16 + srow;
      gload16((const char*)&B[(col0 + row) * ldb + k0] + (sslot ^ (((row >> 1) & 3) << 4)),
              &Bs[buf][g * 128 + w * 16][0]);
    }
  };
  STAGE_A(0, 0);
  STAGE_B(0, 0);                                  // 4 outstanding
  int cur = 0;
  for (int kt = 0; kt < nt; kt++){
    bool more = kt + 1 < nt;
    if (more){
      STAGE_A(cur ^ 1, (kt + 1) * 32);            // 6 outstanding
      asm volatile("s_waitcnt vmcnt(2)" ::: "memory");  // own tile-kt (oldest 4) done
    } else {
      asm volatile("s_waitcnt vmcnt(0)" ::: "memory");
    }
    rawbar();   // all waves' tile-kt loads landed; next-A prefetch survives
    bf16x8 af[8], bfr[4];
    #pragma unroll
    for (int i = 0; i < 8; i++){
      int row = wm * 128 + i * 16 + lr;
      af[i] = __builtin_bit_cast(bf16x8, *(const uint4*)(
          (const char*)&As[cur][0][0] + row * 64 + ((koct * 16) ^ (((row >> 1) & 3) << 4))));
    }
    #pragma unroll
    for (int j = 0; j < 4; j++){
      int row = wn * 64 + j * 16 + lr;
      bfr[j] = __builtin_bit_cast(bf16x8, *(const uint4*)(
          (const char*)&Bs[cur][0][0] + row * 64 + ((koct * 16) ^ (((row >> 1) & 3) << 4))));
    }
    if (more) STAGE_B(cur ^ 1, (kt + 1) * 32);    // issue B after reads, before MFMA
    __builtin_amdgcn_s_setprio(1);
    #pragma unroll
    for (int i = 0; i < 8; i++)
      #pragma unroll
      for (int j = 0; j < 4; j++)
        acc[i][j] = __builtin_amdgcn_mfma_f32_16x16x32_bf16(af[i], bfr[j], acc[i][j], 0, 0, 0);
    __builtin_amdgcn_s_setprio(0);
    rawbar();   // all waves done reading cur before it is restaged
    cur ^= 1;
  }
  #pragma unroll
  for (int i = 0; i < 8; i++){
    long rbase = row0 + wm * 128 + i * 16 + koct * 4;
    #pragma unroll
    for (int j = 0; j < 4; j++){
      long cc = col0 + wn * 64 + j * 16 + lr;
      #pragma unroll
      for (int q = 0; q < 4; q++)
        C[(rbase + q) * ldc + cc] = acc[i][j][q];
    }
  }
}

extern "C" void kernel_launch(void* const* d_in, const int* in_sizes, int n_in,
                              void* d_out, int out_size, void* d_ws, size_t ws_size,
                              hipStream_t stream){
  const int*   idx    = (const int*)d_in[0];
  const float* tok    = (const float*)d_in[1];
  const float* pos    = (const float*)d_in[2];
  const float* r_w1   = (const float*)d_in[3];
  const float* r_b1   = (const float*)d_in[4];
  const float* r_w2   = (const float*)d_in[5];
  const float* r_b2   = (const float*)d_in[6];
  const float* ln1_s  = (const float*)d_in[7];
  const float* ln1_b  = (const float*)d_in[8];
  const float* qkv_w  = (const float*)d_in[9];
  const float* proj_w = (const float*)d_in[10];
  const float* proj_b = (const float*)d_in[11];
  const float* ln2_s  = (const float*)d_in[12];
  const float* ln2_b  = (const float*)d_in[13];
  const float* f_w1   = (const float*)d_in[14];
  const float* f_b1   = (const float*)d_in[15];
  const float* f_w2   = (const float*)d_in[16];
  const float* f_b2   = (const float*)d_in[17];
  const float* lnf_s  = (const float*)d_in[18];
  const float* lnf_b  = (const float*)d_in[19];
  const float* head_w = (const float*)d_in[20];
  float* logits = (float*)d_out;

  char* w = (char*)d_ws;
  size_t off = 0;
  auto alloc = [&](size_t bytes)->char*{ char* p = w + off; off += (bytes + 255) & ~(size_t)255; return p; };
  u16*   wqT  = (u16*)  alloc(2304ull * 768 * 2);
  u16*   wpT  = (u16*)  alloc(768ull * 768 * 2);
  u16*   wf1T = (u16*)  alloc(3072ull * 768 * 2);
  u16*   wf2T = (u16*)  alloc(768ull * 3072 * 2);
  u16*   whd  = (u16*)  alloc(32000ull * 768 * 2);
  float* h    = (float*)alloc(2048ull * 768 * 4);
  float* outb = (float*)alloc(2048ull * 768 * 4);
  u16*   y    = (u16*)  alloc(2048ull * 768 * 2);
  u16*   qkv  = (u16*)  alloc(2048ull * 2304 * 2);
  u16*   o    = (u16*)  alloc(2048ull * 768 * 2);
  u16*   ffh  = (u16*)  alloc(2048ull * 3072 * 2);
  u16*   Vt   = (u16*)  alloc(24ull * 64 * 1024 * 2);
  float* rh   = (float*)alloc(2048ull * 384 * 4);
  int*   sel  = (int*)  alloc(2048 * 4);
  u16*   Sf   = (u16*)  alloc(4ull * 2048 * 768 * 2);   // split-K partials (bf16) — same size as round 14
  (void)in_sizes; (void)n_in; (void)out_size; (void)ws_size;

  dim3 b256(256), b64(64);
  k_wt<<<dim3(24, 72), b256, 0, stream>>>(qkv_w,  wqT,  768, 2304);
  k_wt<<<dim3(24, 24), b256, 0, stream>>>(proj_w, wpT,  768, 768);
  k_wt<<<dim3(24, 96), b256, 0, stream>>>(f_w1,   wf1T, 768, 3072);
  k_wt<<<dim3(96, 24), b256, 0, stream>>>(f_w2,   wf2T, 3072, 768);
  k_conv<<<24000, b256, 0, stream>>>(head_w, whd, 6144000);
  k_embed<<<2048, b256, 0, stream>>>(idx, tok, pos, h);
  k_r1<<<dim3(32, 6), b256, 0, stream>>>(h, r_w1, r_b1, rh);
  k_r2<<<2048, b64, 0, stream>>>(rh, r_w2, r_b2, sel);
  k_ln<<<2048, b256, 0, stream>>>(h, ln1_s, ln1_b, y);

  long f1off = (long)(Sf - ffh);   // element offset: f1 partial z=0 -> ffh, z=1 -> Sf

  for (int d = 0; d < 4; ++d){
    // qkv = y @ wqT^T ; V region written transposed into Vt
    k_gemm1<<<dim3(32, 36), b64, 0, stream>>>(
        y, 768, 0, 0, wqT, 768, 0, 0, qkv, 2304, 0, 0,
        nullptr, nullptr, 0, 768, 12, 0, 1 | 16, Vt);
    // fused causal attention -> o
    k_attn<<<dim3(16, 24), b256, 0, stream>>>(qkv, Vt, o);
    // proj: split-K 2 -> bf16 partials, reduce + bias + resid -> h, fused ln2 -> y
    k_gemm1<<<dim3(32, 12, 2), b64, 0, stream>>>(
        o, 768, 0, 0, wpT, 768, 0, 0, Sf, 768, 2048ll * 768, 0,
        nullptr, nullptr, 0, 768, 12, 384, 1 | 16, nullptr);
    k_redln<<<2048, b256, 0, stream>>>(Sf, 2, proj_b, h, h, ln2_s, ln2_b, y,
                                       nullptr, nullptr, 0);
    // f1: split-K 2 -> bf16 partials; z=0 lands in ffh, z=1 in Sf (no new workspace)
    k_gemm1<<<dim3(32, 48, 2), b64, 0, stream>>>(
        y, 768, 0, 0, wf1T, 768, 0, 0, ffh, 3072, f1off, 0,
        nullptr, nullptr, 0, 768, 12, 384, 1 | 16, nullptr);
    k_redg2<<<2048, b256, 0, stream>>>(Sf, f_b1, ffh);
    // f2: split-K 4 -> bf16 partials, reduce -> h, depth-select -> outb, fused ln1 -> y
    k_gemm1<<<dim3(32, 12, 4), b64, 0, stream>>>(
        ffh, 3072, 0, 0, wf2T, 3072, 0, 0, Sf, 768, 2048ll * 768, 0,
        nullptr, nullptr, 0, 3072, 12, 768, 1 | 16, nullptr);
    k_redln<<<2048, b256, 0, stream>>>(Sf, 4, f_b2, h, h, ln1_s, ln1_b, y,
                                       sel, outb, d);
  }
  k_ln<<<2048, b256, 0, stream>>>(outb, lnf_s, lnf_b, y);
  k_head<<<dim3(8, 125), dim3(512), 0, stream>>>(y, whd, logits);
}

// Round 17
// 888.066 us; speedup vs baseline: 1.0218x; 1.0218x over previous
//
#include <hip/hip_runtime.h>
#include <hip/hip_bf16.h>

typedef unsigned short u16;
typedef __bf16 bf16x8 __attribute__((ext_vector_type(8)));
typedef float f32x4 __attribute__((ext_vector_type(4)));

#define DEVINL __device__ __forceinline__

DEVINL u16 f2b(float f){
  unsigned u = __float_as_uint(f);
  u += 0x7FFFu + ((u >> 16) & 1u);   // RNE
  return (u16)(u >> 16);
}
DEVINL float b2f(u16 b){ return __uint_as_float(((unsigned)b) << 16); }

DEVINL void gload16(const void* g, void* l){
  __builtin_amdgcn_global_load_lds(
      (const __attribute__((address_space(1))) unsigned*)g,
      (__attribute__((address_space(3))) unsigned*)l, 16, 0, 0);
}

// raw barrier: does NOT drain vmcnt (unlike __syncthreads) — counted prefetch survives.
DEVINL void rawbar(){
  __builtin_amdgcn_sched_barrier(0);
  __builtin_amdgcn_s_barrier();
  __builtin_amdgcn_sched_barrier(0);
}

// ---------------- embeddings ----------------
__global__ __launch_bounds__(256) void k_embed(const int* __restrict__ idx,
    const float* __restrict__ tok, const float* __restrict__ pos, float* __restrict__ h){
  int r = blockIdx.x, t = threadIdx.x;
  int token = idx[r];
  const float* tr = tok + (long)token * 768;
  const float* pr = pos + (long)(r & 1023) * 768;
  float* hr = h + (long)r * 768;
  hr[t]       = tr[t]       + pr[t];
  hr[t + 256] = tr[t + 256] + pr[t + 256];
  hr[t + 512] = tr[t + 512] + pr[t + 512];
}

// ---------------- layernorm fp32 -> bf16 ----------------
__global__ __launch_bounds__(256) void k_ln(const float* __restrict__ X,
    const float* __restrict__ s, const float* __restrict__ b, u16* __restrict__ Y){
  int r = blockIdx.x, t = threadIdx.x;
  const float* x = X + (long)r * 768;
  float v0 = x[t], v1 = x[t + 256], v2 = x[t + 512];
  float sum = v0 + v1 + v2;
  __shared__ float tmp[4];
  #pragma unroll
  for (int o = 32; o; o >>= 1) sum += __shfl_xor(sum, o);
  int wave = t >> 6;
  if ((t & 63) == 0) tmp[wave] = sum;
  __syncthreads();
  sum = tmp[0] + tmp[1] + tmp[2] + tmp[3];
  float m = sum * (1.f / 768.f);
  float d0 = v0 - m, d1 = v1 - m, d2 = v2 - m;
  float sq = d0 * d0 + d1 * d1 + d2 * d2;
  #pragma unroll
  for (int o = 32; o; o >>= 1) sq += __shfl_xor(sq, o);
  __syncthreads();
  if ((t & 63) == 0) tmp[wave] = sq;
  __syncthreads();
  sq = tmp[0] + tmp[1] + tmp[2] + tmp[3];
  float rs = rsqrtf(sq * (1.f / 768.f) + 1e-5f);
  u16* y = Y + (long)r * 768;
  y[t]       = f2b(d0 * rs * s[t]       + b[t]);
  y[t + 256] = f2b(d1 * rs * s[t + 256] + b[t + 256]);
  y[t + 512] = f2b(d2 * rs * s[t + 512] + b[t + 512]);
}

// ---------------- weight transpose + fp32->bf16 ----------------
__global__ __launch_bounds__(256) void k_wt(const float* __restrict__ W, u16* __restrict__ Wt,
                                            int K, int N){
  __shared__ float tile[32][33];
  int kb = blockIdx.x * 32, nb = blockIdx.y * 32;
  int tx = threadIdx.x & 31, ty = threadIdx.x >> 5;
  #pragma unroll
  for (int i = 0; i < 32; i += 8) tile[ty + i][tx] = W[(long)(kb + ty + i) * N + nb + tx];
  __syncthreads();
  #pragma unroll
  for (int i = 0; i < 32; i += 8) Wt[(long)(nb + ty + i) * K + kb + tx] = f2b(tile[tx][ty + i]);
}

// ---------------- fp32 -> bf16 convert ----------------
__global__ __launch_bounds__(256) void k_conv(const float* __restrict__ W, u16* __restrict__ O, long n4){
  long i = (long)blockIdx.x * 256 + threadIdx.x;
  if (i >= n4) return;
  float4 v = ((const float4*)W)[i];
  unsigned lo = (unsigned)f2b(v.x) | ((unsigned)f2b(v.y) << 16);
  unsigned hi = (unsigned)f2b(v.z) | ((unsigned)f2b(v.w) << 16);
  ((uint2*)O)[i] = make_uint2(lo, hi);
}

// ---------------- router GEMM1 (fp32) ----------------
__global__ __launch_bounds__(256) void k_r1(const float* __restrict__ A, const float* __restrict__ B,
    const float* __restrict__ bias, float* __restrict__ C){
  __shared__ float As[64][17];
  __shared__ float Bs[16][65];
  int r0 = blockIdx.x * 64, c0 = blockIdx.y * 64;
  int t = threadIdx.x;
  int tx = t & 15, ty = t >> 4;
  float acc[4][4] = {};
  for (int k0 = 0; k0 < 768; k0 += 16){
    #pragma unroll
    for (int i = 0; i < 4; i++){ int e = i * 256 + t; As[e >> 4][e & 15] = A[(long)(r0 + (e >> 4)) * 768 + k0 + (e & 15)]; }
    #pragma unroll
    for (int i = 0; i < 4; i++){ int e = i * 256 + t; Bs[e >> 6][e & 63] = B[(long)(k0 + (e >> 6)) * 384 + c0 + (e & 63)]; }
    __syncthreads();
    #pragma unroll
    for (int kk = 0; kk < 16; kk++){
      float a[4], bb[4];
      #pragma unroll
      for (int i = 0; i < 4; i++) a[i] = As[ty * 4 + i][kk];
      #pragma unroll
      for (int j = 0; j < 4; j++) bb[j] = Bs[kk][tx * 4 + j];
      #pragma unroll
      for (int i = 0; i < 4; i++)
        #pragma unroll
        for (int j = 0; j < 4; j++) acc[i][j] += a[i] * bb[j];
    }
    __syncthreads();
  }
  #pragma unroll
  for (int i = 0; i < 4; i++)
    #pragma unroll
    for (int j = 0; j < 4; j++){
      int rr = r0 + ty * 4 + i, cc = c0 + tx * 4 + j;
      float v = acc[i][j] + bias[cc];
      C[(long)rr * 384 + cc] = v > 0.f ? v : 0.f;
    }
}

// ---------------- router GEMM2 + argmax (fp32) ----------------
__global__ __launch_bounds__(64) void k_r2(const float* __restrict__ rh, const float* __restrict__ w2,
    const float* __restrict__ b2, int* __restrict__ sel){
  int tkn = blockIdx.x, l = threadIdx.x;
  float s0 = 0, s1 = 0, s2 = 0, s3 = 0;
  const float* r = rh + (long)tkn * 384;
  for (int k = l; k < 384; k += 64){
    float rv = r[k];
    float4 w = ((const float4*)w2)[k];
    s0 += rv * w.x; s1 += rv * w.y; s2 += rv * w.z; s3 += rv * w.w;
  }
  #pragma unroll
  for (int o = 32; o; o >>= 1){
    s0 += __shfl_xor(s0, o); s1 += __shfl_xor(s1, o);
    s2 += __shfl_xor(s2, o); s3 += __shfl_xor(s3, o);
  }
  if (l == 0){
    float v[4] = { s0 + b2[0], s1 + b2[1], s2 + b2[2], s3 + b2[3] };
    int am = 0; float bv = v[0];
    #pragma unroll
    for (int j = 1; j < 4; j++) if (v[j] > bv){ bv = v[j]; am = j; }
    sel[tkn] = am;
  }
}

// ---------------- fused causal flash attention ----------------
__global__ __launch_bounds__(256) void k_attn(
    const u16* __restrict__ qkv, const u16* __restrict__ Vt, u16* __restrict__ o){
  __shared__ __align__(16) u16 Klds[64][64];
  __shared__ __align__(16) u16 Vlds[64][64];
  __shared__ __align__(16) u16 Plds[4][16][72];
  int qt = (gridDim.x - 1) - blockIdx.x;   // long blocks (large qt) launch first
  int bh = blockIdx.y;
  int b = bh / 12, hh = bh % 12;
  int t = threadIdx.x, w = t >> 6, lane = t & 63;
  int lr = lane & 15, koct = lane >> 4;
  int q0 = qt * 64 + w * 16;
  const u16* Qrow = qkv + ((long)(b * 1024 + q0 + lr)) * 2304 + hh * 64;
  bf16x8 qf[2];
  qf[0] = __builtin_bit_cast(bf16x8, *(const uint4*)&Qrow[koct * 8]);
  qf[1] = __builtin_bit_cast(bf16x8, *(const uint4*)&Qrow[32 + koct * 8]);
  f32x4 oacc[4] = {};
  float m_run[4], l_run[4];
  #pragma unroll
  for (int r = 0; r < 4; r++){ m_run[r] = -1e30f; l_run[r] = 0.f; }
  int srow8 = lane >> 3, scolb = (lane & 7) * 16;
  const char* Kbase = (const char*)(qkv + (long)b * 1024 * 2304 + 768 + hh * 64);
  const char* Vbase = (const char*)(Vt + (long)bh * 64 * 1024);
  for (int kvt = 0; kvt <= qt; ++kvt){
    #pragma unroll
    for (int i = 0; i < 2; i++){
      int row = w * 16 + i * 8 + srow8;
      int sb = scolb ^ ((row & 7) << 4);
      gload16(Kbase + (long)(kvt * 64 + row) * 4608 + sb, &Klds[w * 16 + i * 8][0]);
    }
    #pragma unroll
    for (int i = 0; i < 2; i++){
      int row = w * 16 + i * 8 + srow8;
      int sb = scolb ^ ((row & 7) << 4);
      gload16(Vbase + (long)row * 2048 + kvt * 128 + sb, &Vlds[w * 16 + i * 8][0]);
    }
    __syncthreads();
    f32x4 sacc[4] = {};
    #pragma unroll
    for (int j = 0; j < 4; j++){
      #pragma unroll
      for (int f = 0; f < 2; f++){
        int row = 16 * j + lr;
        bf16x8 kf = __builtin_bit_cast(bf16x8, *(const uint4*)(
            (const char*)&Klds[0][0] + row * 128 + ((64 * f + koct * 16) ^ ((row & 7) << 4))));
        sacc[j] = __builtin_amdgcn_mfma_f32_16x16x32_bf16(qf[f], kf, sacc[j], 0, 0, 0);
      }
    }
    bool diag = (kvt == qt);
    float p[4][4];
    #pragma unroll
    for (int r = 0; r < 4; r++){
      int qg = q0 + 4 * koct + r;
      float vj[4];
      #pragma unroll
      for (int j = 0; j < 4; j++){
        int kvg = kvt * 64 + 16 * j + lr;
        float v = sacc[j][r] * 0.125f;
        vj[j] = (!diag || kvg <= qg) ? v : -1e30f;
      }
      float mx = fmaxf(fmaxf(vj[0], vj[1]), fmaxf(vj[2], vj[3]));
      #pragma unroll
      for (int s = 1; s < 16; s <<= 1) mx = fmaxf(mx, __shfl_xor(mx, s));
      float mn = fmaxf(m_run[r], mx);
      float sc = __expf(m_run[r] - mn);
      float rs = 0.f;
      #pragma unroll
      for (int j = 0; j < 4; j++){ p[j][r] = __expf(vj[j] - mn); rs += p[j][r]; }
      #pragma unroll
      for (int s = 1; s < 16; s <<= 1) rs += __shfl_xor(rs, s);
      l_run[r] = l_run[r] * sc + rs;
      m_run[r] = mn;
      #pragma unroll
      for (int j = 0; j < 4; j++) oacc[j][r] *= sc;
    }
    #pragma unroll
    for (int r = 0; r < 4; r++)
      #pragma unroll
      for (int j = 0; j < 4; j++)
        Plds[w][4 * koct + r][16 * j + lr] = f2b(p[j][r]);
    bf16x8 pf[2];
    pf[0] = __builtin_bit_cast(bf16x8, *(const uint4*)&Plds[w][lr][koct * 8]);
    pf[1] = __builtin_bit_cast(bf16x8, *(const uint4*)&Plds[w][lr][32 + koct * 8]);
    #pragma unroll
    for (int j = 0; j < 4; j++){
      #pragma unroll
      for (int f = 0; f < 2; f++){
        int row = 16 * j + lr;
        bf16x8 vf = __builtin_bit_cast(bf16x8, *(const uint4*)(
            (const char*)&Vlds[0][0] + row * 128 + ((64 * f + koct * 16) ^ ((row & 7) << 4))));
        oacc[j] = __builtin_amdgcn_mfma_f32_16x16x32_bf16(pf[f], vf, oacc[j], 0, 0, 0);
      }
    }
    __syncthreads();
  }
  float inv[4];
  #pragma unroll
  for (int r = 0; r < 4; r++) inv[r] = 1.f / l_run[r];
  #pragma unroll
  for (int j = 0; j < 4; j++){
    #pragma unroll
    for (int r = 0; r < 4; r++){
      int tq = b * 1024 + q0 + 4 * koct + r;
      o[(long)tq * 768 + hh * 64 + 16 * j + lr] = f2b(oacc[j][r] * inv[r]);
    }
  }
}

// ---------------- split-K reduce (bf16 partials) + bias + resid -> h; fused LN -> y; depth-select ----------------
__global__ __launch_bounds__(256) void k_redln(const u16* __restrict__ P, int nparts,
    const float* __restrict__ bias, const float* __restrict__ resid, float* __restrict__ outh,
    const float* __restrict__ ls, const float* __restrict__ lb, u16* __restrict__ Y,
    const int* __restrict__ sel, float* __restrict__ outb, int d){
  int r = blockIdx.x, t = threadIdx.x;
  float v0, v1, v2;
  {
    float a0 = bias[t]       + resid[(long)r * 768 + t];
    float a1 = bias[t + 256] + resid[(long)r * 768 + t + 256];
    float a2 = bias[t + 512] + resid[(long)r * 768 + t + 512];
    for (int p = 0; p < nparts; p++){
      const u16* pr = P + ((long)p * 2048 + r) * 768;
      a0 += b2f(pr[t]); a1 += b2f(pr[t + 256]); a2 += b2f(pr[t + 512]);
    }
    v0 = a0; v1 = a1; v2 = a2;
  }
  float* hr = outh + (long)r * 768;
  hr[t] = v0; hr[t + 256] = v1; hr[t + 512] = v2;
  if (sel && sel[r] == d){
    float* orow = outb + (long)r * 768;
    orow[t] = v0; orow[t + 256] = v1; orow[t + 512] = v2;
  }
  float sum = v0 + v1 + v2;
  __shared__ float tmp[4];
  #pragma unroll
  for (int o = 32; o; o >>= 1) sum += __shfl_xor(sum, o);
  int wave = t >> 6;
  if ((t & 63) == 0) tmp[wave] = sum;
  __syncthreads();
  sum = tmp[0] + tmp[1] + tmp[2] + tmp[3];
  float m = sum * (1.f / 768.f);
  float d0 = v0 - m, d1 = v1 - m, d2 = v2 - m;
  float sq = d0 * d0 + d1 * d1 + d2 * d2;
  #pragma unroll
  for (int o = 32; o; o >>= 1) sq += __shfl_xor(sq, o);
  __syncthreads();
  if ((t & 63) == 0) tmp[wave] = sq;
  __syncthreads();
  sq = tmp[0] + tmp[1] + tmp[2] + tmp[3];
  float rs = rsqrtf(sq * (1.f / 768.f) + 1e-5f);
  u16* y = Y + (long)r * 768;
  y[t]       = f2b(d0 * rs * ls[t]       + lb[t]);
  y[t + 256] = f2b(d1 * rs * ls[t + 256] + lb[t + 256]);
  y[t + 512] = f2b(d2 * rs * ls[t + 512] + lb[t + 512]);
}

// ---------------- 1-wave 64x64 bf16 MFMA GEMM, dbuf + counted vmcnt, slot-XOR swizzled LDS ----------------
__global__ __launch_bounds__(64) void k_gemm1(
    const u16* __restrict__ A, int lda, long s1A, long s2A,
    const u16* __restrict__ B, int ldb, long s1B, long s2B,
    void* Cv, int ldc, long s1C, long s2C,
    const float* __restrict__ bias,
    const float* __restrict__ resid, int ldr,
    int K, int zdiv, int ksegK, int flags, u16* __restrict__ vtbuf){
  __shared__ __align__(16) u16 As[2][64][32];
  __shared__ __align__(16) u16 Bs[2][64][32];
  int lane = threadIdx.x;
  int bx = blockIdx.x, by = blockIdx.y, bz = blockIdx.z;
  if (flags & 16){
    int nx = gridDim.x, nwg = nx * gridDim.y;
    int lin = by * nx + bx;
    int q = nwg >> 3;                       // requires nwg % 8 == 0
    int nl = (lin & 7) * q + (lin >> 3);
    bx = nl % nx; by = nl / nx;
  }
  int row0 = bx * 64, col0 = by * 64;
  int zq = bz / zdiv, zr = bz % zdiv;
  A += zq * s2A + (long)zr * s1A;
  B += zq * s2B + (long)zr * s1B;
  long coff = zq * s2C + (long)zr * s1C;
  int kstart = 0, Klim = K;
  if (ksegK > 0){ kstart = bz * ksegK; Klim = kstart + ksegK; }
  f32x4 acc[4][4] = {};
  int lr = lane & 15;
  int lkb = (lane >> 4) * 16;                       // 16B slot (bytes) within 64B row
  int srow = lane >> 2, scol = (lane & 3) * 16;
  int sg = ((srow >> 1) & 3) << 4;                  // source inverse-swizzle for this lane's row
  int rg = ((lr >> 1) & 3) << 4;                    // read swizzle for this lane's fragment row
  int nt = (Klim - kstart) >> 5;
  auto STAGE = [&](int buf, int k0){
    #pragma unroll
    for (int i = 0; i < 4; i++)
      gload16((const char*)&A[(long)(row0 + i * 16 + srow) * lda + k0] + (scol ^ sg), &As[buf][i * 16][0]);
    #pragma unroll
    for (int i = 0; i < 4; i++)
      gload16((const char*)&B[(long)(col0 + i * 16 + srow) * ldb + k0] + (scol ^ sg), &Bs[buf][i * 16][0]);
  };
  STAGE(0, kstart);
  int cur = 0;
  for (int t = 0; t < nt; t++){
    if (t + 1 < nt){
      STAGE(cur ^ 1, kstart + ((t + 1) << 5));
      asm volatile("s_waitcnt vmcnt(8)" ::: "memory");
    } else {
      asm volatile("s_waitcnt vmcnt(0)" ::: "memory");
    }
    __builtin_amdgcn_sched_barrier(0);
    bf16x8 af[4], bb[4];
    #pragma unroll
    for (int i = 0; i < 4; i++)
      af[i] = __builtin_bit_cast(bf16x8, *(const uint4*)(
          (const char*)&As[cur][i * 16 + lr][0] + (lkb ^ rg)));
    #pragma unroll
    for (int j = 0; j < 4; j++)
      bb[j] = __builtin_bit_cast(bf16x8, *(const uint4*)(
          (const char*)&Bs[cur][j * 16 + lr][0] + (lkb ^ rg)));
    #pragma unroll
    for (int i = 0; i < 4; i++)
      #pragma unroll
      for (int j = 0; j < 4; j++)
        acc[i][j] = __builtin_amdgcn_mfma_f32_16x16x32_bf16(af[i], bb[j], acc[i][j], 0, 0, 0);
    __builtin_amdgcn_sched_barrier(0);
    cur ^= 1;
  }
  bool vmode = (vtbuf != nullptr) && (col0 >= 1536);
  if (vmode){
    #pragma unroll
    for (int i = 0; i < 4; i++){
      int rbase = row0 + i * 16 + ((lane >> 4) << 2);
      int b = rbase >> 10, tt = rbase & 1023;
      #pragma unroll
      for (int j = 0; j < 4; j++){
        int cc = col0 + j * 16 + lr;
        int hh = (cc - 1536) >> 6, dd = (cc - 1536) & 63;
        unsigned lo = (unsigned)f2b(acc[i][j][0]) | ((unsigned)f2b(acc[i][j][1]) << 16);
        unsigned hi = (unsigned)f2b(acc[i][j][2]) | ((unsigned)f2b(acc[i][j][3]) << 16);
        *(uint2*)&vtbuf[((long)(b * 12 + hh) * 64 + dd) * 1024 + tt] = make_uint2(lo, hi);
      }
    }
    return;
  }
  #pragma unroll
  for (int i = 0; i < 4; i++){
    int rbase = row0 + i * 16 + ((lane >> 4) << 2);
    #pragma unroll
    for (int j = 0; j < 4; j++){
      int cc = col0 + j * 16 + lr;
      #pragma unroll
      for (int q = 0; q < 4; q++){
        int rr = rbase + q;
        float v = acc[i][j][q];
        if (bias) v += bias[cc];
        if (flags & 2) v = 0.5f * v * (1.f + erff(v * 0.70710678118654752f));
        if (resid) v += resid[(long)rr * ldr + cc];
        if (flags & 1) ((u16*)Cv)[coff + (long)rr * ldc + cc] = f2b(v);
        else           ((float*)Cv)[coff + (long)rr * ldc + cc] = v;
      }
    }
  }
}

// ---------------- head GEMM: 256x256, 8 waves, BK=32, 64KB LDS (2 blocks/CU), counted vmcnt + RAW barriers ----------------
// C[2048,32000] fp32 = A[2048,768]bf16 @ B[32000,768]bf16^T
__global__ __launch_bounds__(512, 2) void k_head(
    const u16* __restrict__ A, const u16* __restrict__ B, float* __restrict__ C){
  __shared__ __align__(16) u16 As[2][256][32];   // 16 KB per buf
  __shared__ __align__(16) u16 Bs[2][256][32];   // total 64 KB -> 2 blocks/CU
  const int lda = 768, ldb = 768, ldc = 32000;
  int t = threadIdx.x, w = t >> 6, lane = t & 63;
  int wm = w >> 2, wn = w & 3;                   // 2 x 4 wave grid
  int bx = blockIdx.x, by = blockIdx.y;
  {
    int nx = gridDim.x, nwg = nx * gridDim.y;    // 8*125 = 1000, %8 == 0
    int lin = by * nx + bx;
    int q = nwg >> 3;
    int nl = (lin & 7) * q + (lin >> 3);
    bx = nl % nx; by = nl / nx;
  }
  long row0 = (long)bx * 256, col0 = (long)by * 256;
  int srow = lane >> 2, sslot = (lane & 3) * 16;
  int lr = lane & 15, koct = lane >> 4;
  f32x4 acc[8][4] = {};
  const int nt = 24;                             // K = 768 = 24 * 32
  auto STAGE_A = [&](int buf, int k0){
    #pragma unroll
    for (int g = 0; g < 2; g++){
      int row = g * 128 + w * 16 + srow;
      gload16((const char*)&A[(row0 + row) * lda + k0] + (sslot ^ (((row >> 1) & 3) << 4)),
              &As[buf][g * 128 + w * 16][0]);
    }
  };
  auto STAGE_B = [&](int buf, int k0){
    #pragma unroll
    for (int g = 0; g < 2; g++){
      int row = g * 128 + w * 16 + srow;
      gload16((const char*)&B[(col0 + row) * ldb + k0] + (sslot ^ (((row >> 1) & 3) << 4)),
              &Bs[buf][g * 128 + w * 16][0]);
    }
  };
  STAGE_A(0, 0);
  STAGE_B(0, 0);                                  // 4 outstanding
  int cur = 0;
  for (int kt = 0; kt < nt; kt++){
    bool more = kt + 1 < nt;
    if (more){
      STAGE_A(cur ^ 1, (kt + 1) * 32);            // 6 outstanding
      asm volatile("s_waitcnt vmcnt(2)" ::: "memory");  // own tile-kt (oldest 4) done
    } else {
      asm volatile("s_waitcnt vmcnt(0)" ::: "memory");
    }
    rawbar();   // all waves' tile-kt loads landed; next-A prefetch survives
    bf16x8 af[8], bfr[4];
    #pragma unroll
    for (int i = 0; i < 8; i++){
      int row = wm * 128 + i * 16 + lr;
      af[i] = __builtin_bit_cast(bf16x8, *(const uint4*)(
          (const char*)&As[cur][0][0] + row * 64 + ((koct * 16) ^ (((row >> 1) & 3) << 4))));
    }
    #pragma unroll
    for (int j = 0; j < 4; j++){
      int row = wn * 64 + j * 16 + lr;
      bfr[j] = __builtin_bit_cast(bf16x8, *(const uint4*)(
          (const char*)&Bs[cur][0][0] + row * 64 + ((koct * 16) ^ (((row >> 1) & 3) << 4))));
    }
    if (more) STAGE_B(cur ^ 1, (kt + 1) * 32);    // issue B after reads, before MFMA
    __builtin_amdgcn_s_setprio(1);
    #pragma unroll
    for (int i = 0; i < 8; i++)
      #pragma unroll
      for (int j = 0; j < 4; j++)
        acc[i][j] = __builtin_amdgcn_mfma_f32_16x16x32_bf16(af[i], bfr[j], acc[i][j], 0, 0, 0);
    __builtin_amdgcn_s_setprio(0);
    rawbar();   // all waves done reading cur before it is restaged
    cur ^= 1;
  }
  #pragma unroll
  for (int i = 0; i < 8; i++){
    long rbase = row0 + wm * 128 + i * 16 + koct * 4;
    #pragma unroll
    for (int j = 0; j < 4; j++){
      long cc = col0 + wn * 64 + j * 16 + lr;
      #pragma unroll
      for (int q = 0; q < 4; q++)
        C[(rbase + q) * ldc + cc] = acc[i][j][q];
    }
  }
}

extern "C" void kernel_launch(void* const* d_in, const int* in_sizes, int n_in,
                              void* d_out, int out_size, void* d_ws, size_t ws_size,
                              hipStream_t stream){
  const int*   idx    = (const int*)d_in[0];
  const float* tok    = (const float*)d_in[1];
  const float* pos    = (const float*)d_in[2];
  const float* r_w1   = (const float*)d_in[3];
  const float* r_b1   = (const float*)d_in[4];
  const float* r_w2   = (const float*)d_in[5];
  const float* r_b2   = (const float*)d_in[6];
  const float* ln1_s  = (const float*)d_in[7];
  const float* ln1_b  = (const float*)d_in[8];
  const float* qkv_w  = (const float*)d_in[9];
  const float* proj_w = (const float*)d_in[10];
  const float* proj_b = (const float*)d_in[11];
  const float* ln2_s  = (const float*)d_in[12];
  const float* ln2_b  = (const float*)d_in[13];
  const float* f_w1   = (const float*)d_in[14];
  const float* f_b1   = (const float*)d_in[15];
  const float* f_w2   = (const float*)d_in[16];
  const float* f_b2   = (const float*)d_in[17];
  const float* lnf_s  = (const float*)d_in[18];
  const float* lnf_b  = (const float*)d_in[19];
  const float* head_w = (const float*)d_in[20];
  float* logits = (float*)d_out;

  char* w = (char*)d_ws;
  size_t off = 0;
  auto alloc = [&](size_t bytes)->char*{ char* p = w + off; off += (bytes + 255) & ~(size_t)255; return p; };
  u16*   wqT  = (u16*)  alloc(2304ull * 768 * 2);
  u16*   wpT  = (u16*)  alloc(768ull * 768 * 2);
  u16*   wf1T = (u16*)  alloc(3072ull * 768 * 2);
  u16*   wf2T = (u16*)  alloc(768ull * 3072 * 2);
  u16*   whd  = (u16*)  alloc(32000ull * 768 * 2);
  float* h    = (float*)alloc(2048ull * 768 * 4);
  float* outb = (float*)alloc(2048ull * 768 * 4);
  u16*   y    = (u16*)  alloc(2048ull * 768 * 2);
  u16*   qkv  = (u16*)  alloc(2048ull * 2304 * 2);
  u16*   o    = (u16*)  alloc(2048ull * 768 * 2);
  u16*   ffh  = (u16*)  alloc(2048ull * 3072 * 2);
  u16*   Vt   = (u16*)  alloc(24ull * 64 * 1024 * 2);
  float* rh   = (float*)alloc(2048ull * 384 * 4);
  int*   sel  = (int*)  alloc(2048 * 4);
  u16*   Sf   = (u16*)  alloc(4ull * 2048 * 768 * 2);   // split-K partials (bf16)
  (void)in_sizes; (void)n_in; (void)out_size; (void)ws_size;

  dim3 b256(256), b64(64);
  k_wt<<<dim3(24, 72), b256, 0, stream>>>(qkv_w,  wqT,  768, 2304);
  k_wt<<<dim3(24, 24), b256, 0, stream>>>(proj_w, wpT,  768, 768);
  k_wt<<<dim3(24, 96), b256, 0, stream>>>(f_w1,   wf1T, 768, 3072);
  k_wt<<<dim3(96, 24), b256, 0, stream>>>(f_w2,   wf2T, 3072, 768);
  k_conv<<<24000, b256, 0, stream>>>(head_w, whd, 6144000);
  k_embed<<<2048, b256, 0, stream>>>(idx, tok, pos, h);
  k_r1<<<dim3(32, 6), b256, 0, stream>>>(h, r_w1, r_b1, rh);
  k_r2<<<2048, b64, 0, stream>>>(rh, r_w2, r_b2, sel);
  k_ln<<<2048, b256, 0, stream>>>(h, ln1_s, ln1_b, y);

  for (int d = 0; d < 4; ++d){
    // qkv = y @ wqT^T ; V region written transposed into Vt
    k_gemm1<<<dim3(32, 36), b64, 0, stream>>>(
        y, 768, 0, 0, wqT, 768, 0, 0, qkv, 2304, 0, 0,
        nullptr, nullptr, 0, 768, 12, 0, 1 | 16, Vt);
    // fused causal attention -> o
    k_attn<<<dim3(16, 24), b256, 0, stream>>>(qkv, Vt, o);
    // proj: split-K 2 -> bf16 partials, reduce + bias + resid -> h, fused ln2 -> y
    k_gemm1<<<dim3(32, 12, 2), b64, 0, stream>>>(
        o, 768, 0, 0, wpT, 768, 0, 0, Sf, 768, 2048ll * 768, 0,
        nullptr, nullptr, 0, 768, 12, 384, 1 | 16, nullptr);
    k_redln<<<2048, b256, 0, stream>>>(Sf, 2, proj_b, h, h, ln2_s, ln2_b, y,
                                       nullptr, nullptr, 0);
    // f1: bias + gelu, bf16 out (single GEMM, round-14 form)
    k_gemm1<<<dim3(32, 48), b64, 0, stream>>>(
        y, 768, 0, 0, wf1T, 768, 0, 0, ffh, 3072, 0, 0,
        f_b1, nullptr, 0, 768, 12, 0, 1 | 2 | 16, nullptr);
    // f2: split-K 4 -> bf16 partials, reduce -> h, depth-select -> outb, fused ln1 -> y
    k_gemm1<<<dim3(32, 12, 4), b64, 0, stream>>>(
        ffh, 3072, 0, 0, wf2T, 3072, 0, 0, Sf, 768, 2048ll * 768, 0,
        nullptr, nullptr, 0, 3072, 12, 768, 1 | 16, nullptr);
    k_redln<<<2048, b256, 0, stream>>>(Sf, 4, f_b2, h, h, ln1_s, ln1_b, y,
                                       sel, outb, d);
  }
  k_ln<<<2048, b256, 0, stream>>>(outb, lnf_s, lnf_b, y);
  k_head<<<dim3(8, 125), dim3(512), 0, stream>>>(y, whd, logits);
}

// Round 18
// 884.505 us; speedup vs baseline: 1.0259x; 1.0040x over previous
//
#include <hip/hip_runtime.h>
#include <hip/hip_bf16.h>

typedef unsigned short u16;
typedef __bf16 bf16x8 __attribute__((ext_vector_type(8)));
typedef float f32x4 __attribute__((ext_vector_type(4)));

#define DEVINL __device__ __forceinline__

DEVINL u16 f2b(float f){
  unsigned u = __float_as_uint(f);
  u += 0x7FFFu + ((u >> 16) & 1u);   // RNE
  return (u16)(u >> 16);
}
DEVINL float b2f(u16 b){ return __uint_as_float(((unsigned)b) << 16); }

DEVINL void gload16(const void* g, void* l){
  __builtin_amdgcn_global_load_lds(
      (const __attribute__((address_space(1))) unsigned*)g,
      (__attribute__((address_space(3))) unsigned*)l, 16, 0, 0);
}

// raw barrier: does NOT drain vmcnt (unlike __syncthreads) — counted prefetch survives.
DEVINL void rawbar(){
  __builtin_amdgcn_sched_barrier(0);
  __builtin_amdgcn_s_barrier();
  __builtin_amdgcn_sched_barrier(0);
}

// ---------------- embeddings ----------------
__global__ __launch_bounds__(256) void k_embed(const int* __restrict__ idx,
    const float* __restrict__ tok, const float* __restrict__ pos, float* __restrict__ h){
  int r = blockIdx.x, t = threadIdx.x;
  int token = idx[r];
  const float* tr = tok + (long)token * 768;
  const float* pr = pos + (long)(r & 1023) * 768;
  float* hr = h + (long)r * 768;
  hr[t]       = tr[t]       + pr[t];
  hr[t + 256] = tr[t + 256] + pr[t + 256];
  hr[t + 512] = tr[t + 512] + pr[t + 512];
}

// ---------------- layernorm fp32 -> bf16 ----------------
__global__ __launch_bounds__(256) void k_ln(const float* __restrict__ X,
    const float* __restrict__ s, const float* __restrict__ b, u16* __restrict__ Y){
  int r = blockIdx.x, t = threadIdx.x;
  const float* x = X + (long)r * 768;
  float v0 = x[t], v1 = x[t + 256], v2 = x[t + 512];
  float sum = v0 + v1 + v2;
  __shared__ float tmp[4];
  #pragma unroll
  for (int o = 32; o; o >>= 1) sum += __shfl_xor(sum, o);
  int wave = t >> 6;
  if ((t & 63) == 0) tmp[wave] = sum;
  __syncthreads();
  sum = tmp[0] + tmp[1] + tmp[2] + tmp[3];
  float m = sum * (1.f / 768.f);
  float d0 = v0 - m, d1 = v1 - m, d2 = v2 - m;
  float sq = d0 * d0 + d1 * d1 + d2 * d2;
  #pragma unroll
  for (int o = 32; o; o >>= 1) sq += __shfl_xor(sq, o);
  __syncthreads();
  if ((t & 63) == 0) tmp[wave] = sq;
  __syncthreads();
  sq = tmp[0] + tmp[1] + tmp[2] + tmp[3];
  float rs = rsqrtf(sq * (1.f / 768.f) + 1e-5f);
  u16* y = Y + (long)r * 768;
  y[t]       = f2b(d0 * rs * s[t]       + b[t]);
  y[t + 256] = f2b(d1 * rs * s[t + 256] + b[t + 256]);
  y[t + 512] = f2b(d2 * rs * s[t + 512] + b[t + 512]);
}

// ---------------- weight transpose + fp32->bf16 ----------------
__global__ __launch_bounds__(256) void k_wt(const float* __restrict__ W, u16* __restrict__ Wt,
                                            int K, int N){
  __shared__ float tile[32][33];
  int kb = blockIdx.x * 32, nb = blockIdx.y * 32;
  int tx = threadIdx.x & 31, ty = threadIdx.x >> 5;
  #pragma unroll
  for (int i = 0; i < 32; i += 8) tile[ty + i][tx] = W[(long)(kb + ty + i) * N + nb + tx];
  __syncthreads();
  #pragma unroll
  for (int i = 0; i < 32; i += 8) Wt[(long)(nb + ty + i) * K + kb + tx] = f2b(tile[tx][ty + i]);
}

// ---------------- fp32 -> bf16 convert ----------------
__global__ __launch_bounds__(256) void k_conv(const float* __restrict__ W, u16* __restrict__ O, long n4){
  long i = (long)blockIdx.x * 256 + threadIdx.x;
  if (i >= n4) return;
  float4 v = ((const float4*)W)[i];
  unsigned lo = (unsigned)f2b(v.x) | ((unsigned)f2b(v.y) << 16);
  unsigned hi = (unsigned)f2b(v.z) | ((unsigned)f2b(v.w) << 16);
  ((uint2*)O)[i] = make_uint2(lo, hi);
}

// ---------------- router GEMM1 (fp32) ----------------
__global__ __launch_bounds__(256) void k_r1(const float* __restrict__ A, const float* __restrict__ B,
    const float* __restrict__ bias, float* __restrict__ C){
  __shared__ float As[64][17];
  __shared__ float Bs[16][65];
  int r0 = blockIdx.x * 64, c0 = blockIdx.y * 64;
  int t = threadIdx.x;
  int tx = t & 15, ty = t >> 4;
  float acc[4][4] = {};
  for (int k0 = 0; k0 < 768; k0 += 16){
    #pragma unroll
    for (int i = 0; i < 4; i++){ int e = i * 256 + t; As[e >> 4][e & 15] = A[(long)(r0 + (e >> 4)) * 768 + k0 + (e & 15)]; }
    #pragma unroll
    for (int i = 0; i < 4; i++){ int e = i * 256 + t; Bs[e >> 6][e & 63] = B[(long)(k0 + (e >> 6)) * 384 + c0 + (e & 63)]; }
    __syncthreads();
    #pragma unroll
    for (int kk = 0; kk < 16; kk++){
      float a[4], bb[4];
      #pragma unroll
      for (int i = 0; i < 4; i++) a[i] = As[ty * 4 + i][kk];
      #pragma unroll
      for (int j = 0; j < 4; j++) bb[j] = Bs[kk][tx * 4 + j];
      #pragma unroll
      for (int i = 0; i < 4; i++)
        #pragma unroll
        for (int j = 0; j < 4; j++) acc[i][j] += a[i] * bb[j];
    }
    __syncthreads();
  }
  #pragma unroll
  for (int i = 0; i < 4; i++)
    #pragma unroll
    for (int j = 0; j < 4; j++){
      int rr = r0 + ty * 4 + i, cc = c0 + tx * 4 + j;
      float v = acc[i][j] + bias[cc];
      C[(long)rr * 384 + cc] = v > 0.f ? v : 0.f;
    }
}

// ---------------- router GEMM2 + argmax (fp32) ----------------
__global__ __launch_bounds__(64) void k_r2(const float* __restrict__ rh, const float* __restrict__ w2,
    const float* __restrict__ b2, int* __restrict__ sel){
  int tkn = blockIdx.x, l = threadIdx.x;
  float s0 = 0, s1 = 0, s2 = 0, s3 = 0;
  const float* r = rh + (long)tkn * 384;
  for (int k = l; k < 384; k += 64){
    float rv = r[k];
    float4 w = ((const float4*)w2)[k];
    s0 += rv * w.x; s1 += rv * w.y; s2 += rv * w.z; s3 += rv * w.w;
  }
  #pragma unroll
  for (int o = 32; o; o >>= 1){
    s0 += __shfl_xor(s0, o); s1 += __shfl_xor(s1, o);
    s2 += __shfl_xor(s2, o); s3 += __shfl_xor(s3, o);
  }
  if (l == 0){
    float v[4] = { s0 + b2[0], s1 + b2[1], s2 + b2[2], s3 + b2[3] };
    int am = 0; float bv = v[0];
    #pragma unroll
    for (int j = 1; j < 4; j++) if (v[j] > bv){ bv = v[j]; am = j; }
    sel[tkn] = am;
  }
}

// ---------------- fused causal flash attention: dbuf K/V + counted vmcnt + raw barriers ----------------
__global__ __launch_bounds__(256) void k_attn(
    const u16* __restrict__ qkv, const u16* __restrict__ Vt, u16* __restrict__ o){
  __shared__ __align__(16) u16 Klds[2][64][64];
  __shared__ __align__(16) u16 Vlds[2][64][64];
  __shared__ __align__(16) u16 Plds[4][16][72];
  int qt = (gridDim.x - 1) - blockIdx.x;   // long blocks (large qt) launch first
  int bh = blockIdx.y;
  int b = bh / 12, hh = bh % 12;
  int t = threadIdx.x, w = t >> 6, lane = t & 63;
  int lr = lane & 15, koct = lane >> 4;
  int q0 = qt * 64 + w * 16;
  const u16* Qrow = qkv + ((long)(b * 1024 + q0 + lr)) * 2304 + hh * 64;
  bf16x8 qf[2];
  qf[0] = __builtin_bit_cast(bf16x8, *(const uint4*)&Qrow[koct * 8]);
  qf[1] = __builtin_bit_cast(bf16x8, *(const uint4*)&Qrow[32 + koct * 8]);
  f32x4 oacc[4] = {};
  float m_run[4], l_run[4];
  #pragma unroll
  for (int r = 0; r < 4; r++){ m_run[r] = -1e30f; l_run[r] = 0.f; }
  int srow8 = lane >> 3, scolb = (lane & 7) * 16;
  const char* Kbase = (const char*)(qkv + (long)b * 1024 * 2304 + 768 + hh * 64);
  const char* Vbase = (const char*)(Vt + (long)bh * 64 * 1024);
  // stage one kv-tile (4 gload16/wave: 2 K rows-pairs + 2 V)
  auto STAGE = [&](int buf, int kvt){
    #pragma unroll
    for (int i = 0; i < 2; i++){
      int row = w * 16 + i * 8 + srow8;
      int sb = scolb ^ ((row & 7) << 4);
      gload16(Kbase + (long)(kvt * 64 + row) * 4608 + sb, &Klds[buf][w * 16 + i * 8][0]);
    }
    #pragma unroll
    for (int i = 0; i < 2; i++){
      int row = w * 16 + i * 8 + srow8;
      int sb = scolb ^ ((row & 7) << 4);
      gload16(Vbase + (long)row * 2048 + kvt * 128 + sb, &Vlds[buf][w * 16 + i * 8][0]);
    }
  };
  STAGE(0, 0);
  int cur = 0;
  for (int kvt = 0; kvt <= qt; ++kvt){
    if (kvt < qt){
      STAGE(cur ^ 1, kvt + 1);
      asm volatile("s_waitcnt vmcnt(4)" ::: "memory");  // own tile-kvt loads done; next 4 in flight
    } else {
      asm volatile("s_waitcnt vmcnt(0)" ::: "memory");
    }
    rawbar();   // all waves' tile-kvt loads landed; prefetch NOT drained
    f32x4 sacc[4] = {};
    #pragma unroll
    for (int j = 0; j < 4; j++){
      #pragma unroll
      for (int f = 0; f < 2; f++){
        int row = 16 * j + lr;
        bf16x8 kf = __builtin_bit_cast(bf16x8, *(const uint4*)(
            (const char*)&Klds[cur][0][0] + row * 128 + ((64 * f + koct * 16) ^ ((row & 7) << 4))));
        sacc[j] = __builtin_amdgcn_mfma_f32_16x16x32_bf16(qf[f], kf, sacc[j], 0, 0, 0);
      }
    }
    bool diag = (kvt == qt);
    float p[4][4];
    #pragma unroll
    for (int r = 0; r < 4; r++){
      int qg = q0 + 4 * koct + r;
      float vj[4];
      #pragma unroll
      for (int j = 0; j < 4; j++){
        int kvg = kvt * 64 + 16 * j + lr;
        float v = sacc[j][r] * 0.125f;
        vj[j] = (!diag || kvg <= qg) ? v : -1e30f;
      }
      float mx = fmaxf(fmaxf(vj[0], vj[1]), fmaxf(vj[2], vj[3]));
      #pragma unroll
      for (int s = 1; s < 16; s <<= 1) mx = fmaxf(mx, __shfl_xor(mx, s));
      float mn = fmaxf(m_run[r], mx);
      float sc = __expf(m_run[r] - mn);
      float rs = 0.f;
      #pragma unroll
      for (int j = 0; j < 4; j++){ p[j][r] = __expf(vj[j] - mn); rs += p[j][r]; }
      #pragma unroll
      for (int s = 1; s < 16; s <<= 1) rs += __shfl_xor(rs, s);
      l_run[r] = l_run[r] * sc + rs;
      m_run[r] = mn;
      #pragma unroll
      for (int j = 0; j < 4; j++) oacc[j][r] *= sc;
    }
    #pragma unroll
    for (int r = 0; r < 4; r++)
      #pragma unroll
      for (int j = 0; j < 4; j++)
        Plds[w][4 * koct + r][16 * j + lr] = f2b(p[j][r]);
    bf16x8 pf[2];
    pf[0] = __builtin_bit_cast(bf16x8, *(const uint4*)&Plds[w][lr][koct * 8]);
    pf[1] = __builtin_bit_cast(bf16x8, *(const uint4*)&Plds[w][lr][32 + koct * 8]);
    #pragma unroll
    for (int j = 0; j < 4; j++){
      #pragma unroll
      for (int f = 0; f < 2; f++){
        int row = 16 * j + lr;
        bf16x8 vf = __builtin_bit_cast(bf16x8, *(const uint4*)(
            (const char*)&Vlds[cur][0][0] + row * 128 + ((64 * f + koct * 16) ^ ((row & 7) << 4))));
        oacc[j] = __builtin_amdgcn_mfma_f32_16x16x32_bf16(pf[f], vf, oacc[j], 0, 0, 0);
      }
    }
    rawbar();   // all waves done reading cur before it is restaged next iteration
    cur ^= 1;
  }
  float inv[4];
  #pragma unroll
  for (int r = 0; r < 4; r++) inv[r] = 1.f / l_run[r];
  #pragma unroll
  for (int j = 0; j < 4; j++){
    #pragma unroll
    for (int r = 0; r < 4; r++){
      int tq = b * 1024 + q0 + 4 * koct + r;
      o[(long)tq * 768 + hh * 64 + 16 * j + lr] = f2b(oacc[j][r] * inv[r]);
    }
  }
}

// ---------------- split-K reduce (bf16 partials) + bias + resid -> h; fused LN -> y; depth-select ----------------
__global__ __launch_bounds__(256) void k_redln(const u16* __restrict__ P, int nparts,
    const float* __restrict__ bias, const float* __restrict__ resid, float* __restrict__ outh,
    const float* __restrict__ ls, const float* __restrict__ lb, u16* __restrict__ Y,
    const int* __restrict__ sel, float* __restrict__ outb, int d){
  int r = blockIdx.x, t = threadIdx.x;
  float v0, v1, v2;
  {
    float a0 = bias[t]       + resid[(long)r * 768 + t];
    float a1 = bias[t + 256] + resid[(long)r * 768 + t + 256];
    float a2 = bias[t + 512] + resid[(long)r * 768 + t + 512];
    for (int p = 0; p < nparts; p++){
      const u16* pr = P + ((long)p * 2048 + r) * 768;
      a0 += b2f(pr[t]); a1 += b2f(pr[t + 256]); a2 += b2f(pr[t + 512]);
    }
    v0 = a0; v1 = a1; v2 = a2;
  }
  float* hr = outh + (long)r * 768;
  hr[t] = v0; hr[t + 256] = v1; hr[t + 512] = v2;
  if (sel && sel[r] == d){
    float* orow = outb + (long)r * 768;
    orow[t] = v0; orow[t + 256] = v1; orow[t + 512] = v2;
  }
  float sum = v0 + v1 + v2;
  __shared__ float tmp[4];
  #pragma unroll
  for (int o = 32; o; o >>= 1) sum += __shfl_xor(sum, o);
  int wave = t >> 6;
  if ((t & 63) == 0) tmp[wave] = sum;
  __syncthreads();
  sum = tmp[0] + tmp[1] + tmp[2] + tmp[3];
  float m = sum * (1.f / 768.f);
  float d0 = v0 - m, d1 = v1 - m, d2 = v2 - m;
  float sq = d0 * d0 + d1 * d1 + d2 * d2;
  #pragma unroll
  for (int o = 32; o; o >>= 1) sq += __shfl_xor(sq, o);
  __syncthreads();
  if ((t & 63) == 0) tmp[wave] = sq;
  __syncthreads();
  sq = tmp[0] + tmp[1] + tmp[2] + tmp[3];
  float rs = rsqrtf(sq * (1.f / 768.f) + 1e-5f);
  u16* y = Y + (long)r * 768;
  y[t]       = f2b(d0 * rs * ls[t]       + lb[t]);
  y[t + 256] = f2b(d1 * rs * ls[t + 256] + lb[t + 256]);
  y[t + 512] = f2b(d2 * rs * ls[t + 512] + lb[t + 512]);
}

// ---------------- 1-wave 64x64 bf16 MFMA GEMM, dbuf + counted vmcnt, slot-XOR swizzled LDS ----------------
__global__ __launch_bounds__(64) void k_gemm1(
    const u16* __restrict__ A, int lda, long s1A, long s2A,
    const u16* __restrict__ B, int ldb, long s1B, long s2B,
    void* Cv, int ldc, long s1C, long s2C,
    const float* __restrict__ bias,
    const float* __restrict__ resid, int ldr,
    int K, int zdiv, int ksegK, int flags, u16* __restrict__ vtbuf){
  __shared__ __align__(16) u16 As[2][64][32];
  __shared__ __align__(16) u16 Bs[2][64][32];
  int lane = threadIdx.x;
  int bx = blockIdx.x, by = blockIdx.y, bz = blockIdx.z;
  if (flags & 16){
    int nx = gridDim.x, nwg = nx * gridDim.y;
    int lin = by * nx + bx;
    int q = nwg >> 3;                       // requires nwg % 8 == 0
    int nl = (lin & 7) * q + (lin >> 3);
    bx = nl % nx; by = nl / nx;
  }
  int row0 = bx * 64, col0 = by * 64;
  int zq = bz / zdiv, zr = bz % zdiv;
  A += zq * s2A + (long)zr * s1A;
  B += zq * s2B + (long)zr * s1B;
  long coff = zq * s2C + (long)zr * s1C;
  int kstart = 0, Klim = K;
  if (ksegK > 0){ kstart = bz * ksegK; Klim = kstart + ksegK; }
  f32x4 acc[4][4] = {};
  int lr = lane & 15;
  int lkb = (lane >> 4) * 16;                       // 16B slot (bytes) within 64B row
  int srow = lane >> 2, scol = (lane & 3) * 16;
  int sg = ((srow >> 1) & 3) << 4;                  // source inverse-swizzle for this lane's row
  int rg = ((lr >> 1) & 3) << 4;                    // read swizzle for this lane's fragment row
  int nt = (Klim - kstart) >> 5;
  auto STAGE = [&](int buf, int k0){
    #pragma unroll
    for (int i = 0; i < 4; i++)
      gload16((const char*)&A[(long)(row0 + i * 16 + srow) * lda + k0] + (scol ^ sg), &As[buf][i * 16][0]);
    #pragma unroll
    for (int i = 0; i < 4; i++)
      gload16((const char*)&B[(long)(col0 + i * 16 + srow) * ldb + k0] + (scol ^ sg), &Bs[buf][i * 16][0]);
  };
  STAGE(0, kstart);
  int cur = 0;
  for (int t = 0; t < nt; t++){
    if (t + 1 < nt){
      STAGE(cur ^ 1, kstart + ((t + 1) << 5));
      asm volatile("s_waitcnt vmcnt(8)" ::: "memory");
    } else {
      asm volatile("s_waitcnt vmcnt(0)" ::: "memory");
    }
    __builtin_amdgcn_sched_barrier(0);
    bf16x8 af[4], bb[4];
    #pragma unroll
    for (int i = 0; i < 4; i++)
      af[i] = __builtin_bit_cast(bf16x8, *(const uint4*)(
          (const char*)&As[cur][i * 16 + lr][0] + (lkb ^ rg)));
    #pragma unroll
    for (int j = 0; j < 4; j++)
      bb[j] = __builtin_bit_cast(bf16x8, *(const uint4*)(
          (const char*)&Bs[cur][j * 16 + lr][0] + (lkb ^ rg)));
    #pragma unroll
    for (int i = 0; i < 4; i++)
      #pragma unroll
      for (int j = 0; j < 4; j++)
        acc[i][j] = __builtin_amdgcn_mfma_f32_16x16x32_bf16(af[i], bb[j], acc[i][j], 0, 0, 0);
    __builtin_amdgcn_sched_barrier(0);
    cur ^= 1;
  }
  bool vmode = (vtbuf != nullptr) && (col0 >= 1536);
  if (vmode){
    #pragma unroll
    for (int i = 0; i < 4; i++){
      int rbase = row0 + i * 16 + ((lane >> 4) << 2);
      int b = rbase >> 10, tt = rbase & 1023;
      #pragma unroll
      for (int j = 0; j < 4; j++){
        int cc = col0 + j * 16 + lr;
        int hh = (cc - 1536) >> 6, dd = (cc - 1536) & 63;
        unsigned lo = (unsigned)f2b(acc[i][j][0]) | ((unsigned)f2b(acc[i][j][1]) << 16);
        unsigned hi = (unsigned)f2b(acc[i][j][2]) | ((unsigned)f2b(acc[i][j][3]) << 16);
        *(uint2*)&vtbuf[((long)(b * 12 + hh) * 64 + dd) * 1024 + tt] = make_uint2(lo, hi);
      }
    }
    return;
  }
  #pragma unroll
  for (int i = 0; i < 4; i++){
    int rbase = row0 + i * 16 + ((lane >> 4) << 2);
    #pragma unroll
    for (int j = 0; j < 4; j++){
      int cc = col0 + j * 16 + lr;
      #pragma unroll
      for (int q = 0; q < 4; q++){
        int rr = rbase + q;
        float v = acc[i][j][q];
        if (bias) v += bias[cc];
        if (flags & 2) v = 0.5f * v * (1.f + erff(v * 0.70710678118654752f));
        if (resid) v += resid[(long)rr * ldr + cc];
        if (flags & 1) ((u16*)Cv)[coff + (long)rr * ldc + cc] = f2b(v);
        else           ((float*)Cv)[coff + (long)rr * ldc + cc] = v;
      }
    }
  }
}

// ---------------- head GEMM: 256x256, 8 waves, BK=32, 64KB LDS (2 blocks/CU), counted vmcnt + RAW barriers ----------------
// C[2048,32000] fp32 = A[2048,768]bf16 @ B[32000,768]bf16^T
__global__ __launch_bounds__(512, 2) void k_head(
    const u16* __restrict__ A, const u16* __restrict__ B, float* __restrict__ C){
  __shared__ __align__(16) u16 As[2][256][32];   // 16 KB per buf
  __shared__ __align__(16) u16 Bs[2][256][32];   // total 64 KB -> 2 blocks/CU
  const int lda = 768, ldb = 768, ldc = 32000;
  int t = threadIdx.x, w = t >> 6, lane = t & 63;
  int wm = w >> 2, wn = w & 3;                   // 2 x 4 wave grid
  int bx = blockIdx.x, by = blockIdx.y;
  {
    int nx = gridDim.x, nwg = nx * gridDim.y;    // 8*125 = 1000, %8 == 0
    int lin = by * nx + bx;
    int q = nwg >> 3;
    int nl = (lin & 7) * q + (lin >> 3);
    bx = nl % nx; by = nl / nx;
  }
  long row0 = (long)bx * 256, col0 = (long)by * 256;
  int srow = lane >> 2, sslot = (lane & 3) * 16;
  int lr = lane & 15, koct = lane >> 4;
  f32x4 acc[8][4] = {};
  const int nt = 24;                             // K = 768 = 24 * 32
  auto STAGE_A = [&](int buf, int k0){
    #pragma unroll
    for (int g = 0; g < 2; g++){
      int row = g * 128 + w * 16 + srow;
      gload16((const char*)&A[(row0 + row) * lda + k0] + (sslot ^ (((row >> 1) & 3) << 4)),
              &As[buf][g * 128 + w * 16][0]);
    }
  };
  auto STAGE_B = [&](int buf, int k0){
    #pragma unroll
    for (int g = 0; g < 2; g++){
      int row = g * 128 + w * 16 + srow;
      gload16((const char*)&B[(col0 + row) * ldb + k0] + (sslot ^ (((row >> 1) & 3) << 4)),
              &Bs[buf][g * 128 + w * 16][0]);
    }
  };
  STAGE_A(0, 0);
  STAGE_B(0, 0);                                  // 4 outstanding
  int cur = 0;
  for (int kt = 0; kt < nt; kt++){
    bool more = kt + 1 < nt;
    if (more){
      STAGE_A(cur ^ 1, (kt + 1) * 32);            // 6 outstanding
      asm volatile("s_waitcnt vmcnt(2)" ::: "memory");  // own tile-kt (oldest 4) done
    } else {
      asm volatile("s_waitcnt vmcnt(0)" ::: "memory");
    }
    rawbar();   // all waves' tile-kt loads landed; next-A prefetch survives
    bf16x8 af[8], bfr[4];
    #pragma unroll
    for (int i = 0; i < 8; i++){
      int row = wm * 128 + i * 16 + lr;
      af[i] = __builtin_bit_cast(bf16x8, *(const uint4*)(
          (const char*)&As[cur][0][0] + row * 64 + ((koct * 16) ^ (((row >> 1) & 3) << 4))));
    }
    #pragma unroll
    for (int j = 0; j < 4; j++){
      int row = wn * 64 + j * 16 + lr;
      bfr[j] = __builtin_bit_cast(bf16x8, *(const uint4*)(
          (const char*)&Bs[cur][0][0] + row * 64 + ((koct * 16) ^ (((row >> 1) & 3) << 4))));
    }
    if (more) STAGE_B(cur ^ 1, (kt + 1) * 32);    // issue B after reads, before MFMA
    __builtin_amdgcn_s_setprio(1);
    #pragma unroll
    for (int i = 0; i < 8; i++)
      #pragma unroll
      for (int j = 0; j < 4; j++)
        acc[i][j] = __builtin_amdgcn_mfma_f32_16x16x32_bf16(af[i], bfr[j], acc[i][j], 0, 0, 0);
    __builtin_amdgcn_s_setprio(0);
    rawbar();   // all waves done reading cur before it is restaged
    cur ^= 1;
  }
  #pragma unroll
  for (int i = 0; i < 8; i++){
    long rbase = row0 + wm * 128 + i * 16 + koct * 4;
    #pragma unroll
    for (int j = 0; j < 4; j++){
      long cc = col0 + wn * 64 + j * 16 + lr;
      #pragma unroll
      for (int q = 0; q < 4; q++)
        C[(rbase + q) * ldc + cc] = acc[i][j][q];
    }
  }
}

extern "C" void kernel_launch(void* const* d_in, const int* in_sizes, int n_in,
                              void* d_out, int out_size, void* d_ws, size_t ws_size,
                              hipStream_t stream){
  const int*   idx    = (const int*)d_in[0];
  const float* tok    = (const float*)d_in[1];
  const float* pos    = (const float*)d_in[2];
  const float* r_w1   = (const float*)d_in[3];
  const float* r_b1   = (const float*)d_in[4];
  const float* r_w2   = (const float*)d_in[5];
  const float* r_b2   = (const float*)d_in[6];
  const float* ln1_s  = (const float*)d_in[7];
  const float* ln1_b  = (const float*)d_in[8];
  const float* qkv_w  = (const float*)d_in[9];
  const float* proj_w = (const float*)d_in[10];
  const float* proj_b = (const float*)d_in[11];
  const float* ln2_s  = (const float*)d_in[12];
  const float* ln2_b  = (const float*)d_in[13];
  const float* f_w1   = (const float*)d_in[14];
  const float* f_b1   = (const float*)d_in[15];
  const float* f_w2   = (const float*)d_in[16];
  const float* f_b2   = (const float*)d_in[17];
  const float* lnf_s  = (const float*)d_in[18];
  const float* lnf_b  = (const float*)d_in[19];
  const float* head_w = (const float*)d_in[20];
  float* logits = (float*)d_out;

  char* w = (char*)d_ws;
  size_t off = 0;
  auto alloc = [&](size_t bytes)->char*{ char* p = w + off; off += (bytes + 255) & ~(size_t)255; return p; };
  u16*   wqT  = (u16*)  alloc(2304ull * 768 * 2);
  u16*   wpT  = (u16*)  alloc(768ull * 768 * 2);
  u16*   wf1T = (u16*)  alloc(3072ull * 768 * 2);
  u16*   wf2T = (u16*)  alloc(768ull * 3072 * 2);
  u16*   whd  = (u16*)  alloc(32000ull * 768 * 2);
  float* h    = (float*)alloc(2048ull * 768 * 4);
  float* outb = (float*)alloc(2048ull * 768 * 4);
  u16*   y    = (u16*)  alloc(2048ull * 768 * 2);
  u16*   qkv  = (u16*)  alloc(2048ull * 2304 * 2);
  u16*   o    = (u16*)  alloc(2048ull * 768 * 2);
  u16*   ffh  = (u16*)  alloc(2048ull * 3072 * 2);
  u16*   Vt   = (u16*)  alloc(24ull * 64 * 1024 * 2);
  float* rh   = (float*)alloc(2048ull * 384 * 4);
  int*   sel  = (int*)  alloc(2048 * 4);
  u16*   Sf   = (u16*)  alloc(4ull * 2048 * 768 * 2);   // split-K partials (bf16)
  (void)in_sizes; (void)n_in; (void)out_size; (void)ws_size;

  dim3 b256(256), b64(64);
  k_wt<<<dim3(24, 72), b256, 0, stream>>>(qkv_w,  wqT,  768, 2304);
  k_wt<<<dim3(24, 24), b256, 0, stream>>>(proj_w, wpT,  768, 768);
  k_wt<<<dim3(24, 96), b256, 0, stream>>>(f_w1,   wf1T, 768, 3072);
  k_wt<<<dim3(96, 24), b256, 0, stream>>>(f_w2,   wf2T, 3072, 768);
  k_conv<<<24000, b256, 0, stream>>>(head_w, whd, 6144000);
  k_embed<<<2048, b256, 0, stream>>>(idx, tok, pos, h);
  k_r1<<<dim3(32, 6), b256, 0, stream>>>(h, r_w1, r_b1, rh);
  k_r2<<<2048, b64, 0, stream>>>(rh, r_w2, r_b2, sel);
  k_ln<<<2048, b256, 0, stream>>>(h, ln1_s, ln1_b, y);

  for (int d = 0; d < 4; ++d){
    // qkv = y @ wqT^T ; V region written transposed into Vt
    k_gemm1<<<dim3(32, 36), b64, 0, stream>>>(
        y, 768, 0, 0, wqT, 768, 0, 0, qkv, 2304, 0, 0,
        nullptr, nullptr, 0, 768, 12, 0, 1 | 16, Vt);
    // fused causal attention -> o
    k_attn<<<dim3(16, 24), b256, 0, stream>>>(qkv, Vt, o);
    // proj: split-K 2 -> bf16 partials, reduce + bias + resid -> h, fused ln2 -> y
    k_gemm1<<<dim3(32, 12, 2), b64, 0, stream>>>(
        o, 768, 0, 0, wpT, 768, 0, 0, Sf, 768, 2048ll * 768, 0,
        nullptr, nullptr, 0, 768, 12, 384, 1 | 16, nullptr);
    k_redln<<<2048, b256, 0, stream>>>(Sf, 2, proj_b, h, h, ln2_s, ln2_b, y,
                                       nullptr, nullptr, 0);
    // f1: bias + gelu, bf16 out
    k_gemm1<<<dim3(32, 48), b64, 0, stream>>>(
        y, 768, 0, 0, wf1T, 768, 0, 0, ffh, 3072, 0, 0,
        f_b1, nullptr, 0, 768, 12, 0, 1 | 2 | 16, nullptr);
    // f2: split-K 4 -> bf16 partials, reduce -> h, depth-select -> outb, fused ln1 -> y
    k_gemm1<<<dim3(32, 12, 4), b64, 0, stream>>>(
        ffh, 3072, 0, 0, wf2T, 3072, 0, 0, Sf, 768, 2048ll * 768, 0,
        nullptr, nullptr, 0, 3072, 12, 768, 1 | 16, nullptr);
    k_redln<<<2048, b256, 0, stream>>>(Sf, 4, f_b2, h, h, ln1_s, ln1_b, y,
                                       sel, outb, d);
  }
  k_ln<<<2048, b256, 0, stream>>>(outb, lnf_s, lnf_b, y);
  k_head<<<dim3(8, 125), dim3(512), 0, stream>>>(y, whd, logits);
}